// Round 1
// baseline (901.035 us; speedup 1.0000x reference)
//
#include <hip/hip_runtime.h>

#define VOCABN 5000
#define EMBD   16
#define HIDN   32
#define GATES  128   // 4*HID
#define BATCH  512
#define SEQT   2048

__device__ __forceinline__ float sigm(float x) {
    return __builtin_amdgcn_rcpf(1.0f + __expf(-x));
}
__device__ __forceinline__ float tanh_fast(float x) {
    float s = __builtin_amdgcn_rcpf(1.0f + __expf(-2.0f * x));
    return __builtin_fmaf(2.0f, s, -1.0f);
}

// proj[v*64 + l] = { emb[v]·W[:,l] + bias[l],  emb[v]·W[:,l+64] + bias[l+64] }
__global__ __launch_bounds__(64) void build_proj_kernel(
    const float* __restrict__ emb, const float* __restrict__ W,
    const float* __restrict__ bias, float2* __restrict__ proj)
{
    const int v = blockIdx.x;
    const int l = threadIdx.x;
    float e[EMBD];
#pragma unroll
    for (int k = 0; k < EMBD; ++k) e[k] = emb[v * EMBD + k];
    float a = bias[l];
    float b = bias[l + 64];
#pragma unroll
    for (int k = 0; k < EMBD; ++k) {
        a = __builtin_fmaf(e[k], W[k * GATES + l], a);
        b = __builtin_fmaf(e[k], W[k * GATES + l + 64], b);
    }
    proj[v * 64 + l] = make_float2(a, b);
}

// One 64-lane wave per batch row. Lane l owns gates l and l+64.
__global__ __launch_bounds__(64) void lstm_scan_kernel(
    const int* __restrict__ tokens, const float* __restrict__ rec,
    const float2* __restrict__ proj, float* __restrict__ out)
{
    const int b = blockIdx.x;
    const int l = threadIdx.x;
    __shared__ __align__(16) float hs[HIDN];

    // rec_kernel columns l and l+64 live in registers for the whole scan (64 VGPRs)
    float ra[HIDN], rb[HIDN];
#pragma unroll
    for (int k = 0; k < HIDN; ++k) {
        ra[k] = rec[k * GATES + l];
        rb[k] = rec[k * GATES + l + 64];
    }

    const int* __restrict__ trow = tokens + (size_t)b * SEQT;
    const bool lo = (l < HIDN);

    float c = 0.0f, hval = 0.0f;
    if (lo) hs[l] = 0.0f;
    asm volatile("s_waitcnt lgkmcnt(0)" ::: "memory");
    __builtin_amdgcn_sched_barrier(0);

    // depth-2 prefetch pipeline: token[t+2], proj[token[t+1]]
    int tcur = trow[0];
    int tnxt = trow[1];
    float2 xz = proj[(size_t)tcur * 64 + l];

    for (int t = 0; t < SEQT; ++t) {
        float2 xz_n = proj[(size_t)tnxt * 64 + l];
        const int t2 = t + 2;
        const int tok_nn = trow[t2 < SEQT ? t2 : SEQT - 1];

        // z = xz + h @ rec (columns l and l+64), split accumulators for dep-latency
        float zA0 = xz.x, zB0 = xz.y;
        float zA1 = 0.0f, zB1 = 0.0f;
        const float4* h4 = (const float4*)hs;
#pragma unroll
        for (int q = 0; q < 8; ++q) {
            float4 hv = h4[q];
            const float* hp = (const float*)&hv;
            if ((q & 1) == 0) {
#pragma unroll
                for (int r = 0; r < 4; ++r) {
                    zA0 = __builtin_fmaf(hp[r], ra[4 * q + r], zA0);
                    zB0 = __builtin_fmaf(hp[r], rb[4 * q + r], zB0);
                }
            } else {
#pragma unroll
                for (int r = 0; r < 4; ++r) {
                    zA1 = __builtin_fmaf(hp[r], ra[4 * q + r], zA1);
                    zB1 = __builtin_fmaf(hp[r], rb[4 * q + r], zB1);
                }
            }
        }
        const float zA = zA0 + zA1;
        const float zB = zB0 + zB1;

        // exchange halves: lane j<32 holds (i,g), lane j+32 holds (f,o)
        const float sA = __shfl_xor(zA, 32, 64);
        const float sB = __shfl_xor(zB, 32, 64);
        const float zi = lo ? zA : sA;
        const float zf = lo ? sA : zA;
        const float zg = lo ? zB : sB;
        const float zo = lo ? sB : zB;

        const float ig = sigm(zi);
        const float fg = sigm(zf);
        const float gg = tanh_fast(zg);
        const float og = sigm(zo);
        const float cn = __builtin_fmaf(fg, c, ig * gg);
        const float hn = og * tanh_fast(cn);

        const bool m = (tcur != 0);
        c    = m ? cn : c;
        hval = m ? hn : hval;

        if (lo) hs[l] = hval;
        asm volatile("s_waitcnt lgkmcnt(0)" ::: "memory");
        __builtin_amdgcn_sched_barrier(0);

        tcur = tnxt;
        tnxt = tok_nn;
        xz   = xz_n;
    }

    if (lo) out[(size_t)b * HIDN + l] = hval;
}

extern "C" void kernel_launch(void* const* d_in, const int* in_sizes, int n_in,
                              void* d_out, int out_size, void* d_ws, size_t ws_size,
                              hipStream_t stream)
{
    const int*   tokens = (const int*)d_in[0];
    const float* emb    = (const float*)d_in[1];
    const float* W      = (const float*)d_in[2];
    const float* rec    = (const float*)d_in[3];
    const float* bias   = (const float*)d_in[4];
    float* out = (float*)d_out;
    float2* proj = (float2*)d_ws;   // VOCABN*64 float2 = 2.56 MB

    hipLaunchKernelGGL(build_proj_kernel, dim3(VOCABN), dim3(64), 0, stream,
                       emb, W, bias, proj);
    hipLaunchKernelGGL(lstm_scan_kernel, dim3(BATCH), dim3(64), 0, stream,
                       tokens, rec, proj, out);
}